// Round 11
// baseline (175.131 us; speedup 1.0000x reference)
//
#include <hip/hip_runtime.h>
#include <stdint.h>

typedef unsigned short u16;
typedef u16   u16x4 __attribute__((ext_vector_type(4)));   // 8 B
typedef u16   u16x8 __attribute__((ext_vector_type(8)));   // 16 B
typedef short v8s   __attribute__((ext_vector_type(8)));   // bf16x8 (4 VGPR)
typedef float v4f   __attribute__((ext_vector_type(4)));
typedef float f4    __attribute__((ext_vector_type(4)));

#if __has_builtin(__builtin_amdgcn_exp2f)
#define EXP2F(x) __builtin_amdgcn_exp2f(x)
#else
#define EXP2F(x) exp2f(x)
#endif
#if __has_builtin(__builtin_amdgcn_rcpf)
#define RCPF(x) __builtin_amdgcn_rcpf(x)
#else
#define RCPF(x) (1.0f/(x))
#endif

__device__ __forceinline__ float b2f(u16 u) {
    unsigned int i = ((unsigned int)u) << 16;
    float f; __builtin_memcpy(&f, &i, 4); return f;
}
__device__ __forceinline__ u16 f2b(float f) {
    unsigned int x; __builtin_memcpy(&x, &f, 4);
    x += 0x7fffu + ((x >> 16) & 1u);   // RNE
    return (u16)(x >> 16);
}
// tanh for x >= 0; inf-safe: exp2(big)=inf, rcp(inf)=0 -> exactly 1.
__device__ __forceinline__ float tanhp(float x) {
    float e = EXP2F(2.8853900817779268f * x);   // e^(2x)
    return 1.0f - 2.0f * RCPF(1.0f + e);
}
__device__ __forceinline__ void g2l16(const u16* g, u16* l) {
    __builtin_amdgcn_global_load_lds(
        (const __attribute__((address_space(1))) unsigned int*)g,
        (__attribute__((address_space(3))) unsigned int*)l, 16, 0, 0);
}

// R pre-scale: s^2 = 2/(16*ln2) so stage2's exp2(dot) = e^(2*dot_true/16)
#define RSCALE 0.42466090f

// ---------------- prep: cvt (z=0,1) + wtrans (z=2,3) in ONE dispatch ---------
// cvt:    fp32 [4096][256] -> bf16 [4096][256]
// wtrans: fp32 W[256][4096] -> bf16 T[4096][256]; z=3 (protein W) permutes
//         output row pi(n) = (n&255)*16 + (n>>8) -> stage2's [p*16+h] order.
__global__ __launch_bounds__(256) void prep(
    const float* __restrict__ drug, const float* __restrict__ protein,
    const float* __restrict__ Wd,   const float* __restrict__ Wp,
    u16* __restrict__ Ad, u16* __restrict__ Ap,
    u16* __restrict__ Wtd, u16* __restrict__ Wtp) {
    int z = blockIdx.z;
    if (z < 2) {
        const float* X = z ? protein : drug;
        u16*         O = z ? Ap : Ad;
        size_t i = ((size_t)blockIdx.x * 256 + threadIdx.x) * 4;
        f4 a = *(const f4*)(X + i);
        u16x4 r;
        r[0] = f2b(a[0]); r[1] = f2b(a[1]); r[2] = f2b(a[2]); r[3] = f2b(a[3]);
        *(u16x4*)(O + i) = r;
    } else {
        int zz = (z == 3);
        const float* W = zz ? Wp : Wd;
        u16*         T = zz ? Wtp : Wtd;
        __shared__ u16 t[32][36];
        int k0 = (blockIdx.x & 7) * 32, n0 = (blockIdx.x >> 3) * 32;
        int r = threadIdx.x >> 3, c = (threadIdx.x & 7) * 4;
        f4 v = *(const f4*)(W + (size_t)(k0 + r) * 4096 + n0 + c);
        t[r][c + 0] = f2b(v[0]); t[r][c + 1] = f2b(v[1]);
        t[r][c + 2] = f2b(v[2]); t[r][c + 3] = f2b(v[3]);
        __syncthreads();
        u16x4 o;
        o.x = t[c + 0][r]; o.y = t[c + 1][r]; o.z = t[c + 2][r]; o.w = t[c + 3][r];
        int n = n0 + r;
        int row = zz ? ((n & 255) * 16 + (n >> 8)) : n;
        *(u16x4*)(T + (size_t)row * 256 + k0 + c) = o;
    }
}

// ---------------- GEMM + bias + relu: 256x128 tile, 512 threads --------------
// A row-major bf16 [rows][256]; Bt row-major bf16 [4096][256].
// 8 waves: wm = (wave>>1)*64 (4 m-sub), wn = (wave&1)*64. Per-block staging
// traffic per output HALVED vs 128x128 (R10 post-mortem: books suggest gemm
// is cache-BW/overhead bound). XOR swizzle on global k-chunk keeps both
// staging and ds_read_b128 2-way conflict-free.
// MFMA operand order swapped: mfma(bf, af) -> lane holds one m-row, 4
// consecutive n -> packed 8B stores. Output scaled by RSCALE.
__global__ __launch_bounds__(512, 4) void gemm_relu(
    const u16* __restrict__ A0, const u16* __restrict__ A1,
    const u16* __restrict__ B0, const u16* __restrict__ B1,
    const float* __restrict__ bias0, const float* __restrict__ bias1,
    u16* __restrict__ R0, u16* __restrict__ R1) {
    int z = blockIdx.z;
    const u16*   A    = z ? A1 : A0;
    const u16*   Bt   = z ? B1 : B0;
    const float* bias = z ? bias1 : bias0;
    u16*         R    = z ? R1 : R0;

    __shared__ __align__(16) u16 As[256 * 64];   // 32 KB
    __shared__ __align__(16) u16 Bs[128 * 64];   // 16 KB

    int tid  = threadIdx.x;
    int lane = tid & 63;
    int wave = tid >> 6;                // 0..7
    int m0 = blockIdx.x * 256, n0 = blockIdx.y * 128;
    int wm = (wave >> 1) * 64, wn = (wave & 1) * 64;

    v4f acc[4][4] = {};

    const u16* Ab = A  + (size_t)m0 * 256;
    const u16* Bb = Bt + (size_t)n0 * 256;
    int rsel = lane & 15, kg = lane >> 4;

    for (int kk = 0; kk < 256; kk += 64) {
        __syncthreads();                      // previous iter's readers done
#pragma unroll
        for (int j = 0; j < 4; ++j) {         // As: 2048 chunks
            int f = tid + j * 512;
            int r = f >> 3, cc = f & 7;
            int gc = (cc ^ (r & 7)) * 8;
            g2l16(Ab + (size_t)r * 256 + kk + gc, As + f * 8);
        }
#pragma unroll
        for (int j = 0; j < 2; ++j) {         // Bs: 1024 chunks
            int f = tid + j * 512;
            int r = f >> 3, cc = f & 7;
            int gc = (cc ^ (r & 7)) * 8;
            g2l16(Bb + (size_t)r * 256 + kk + gc, Bs + f * 8);
        }
        __syncthreads();                      // staging complete (vmcnt drained)
#pragma unroll
        for (int h = 0; h < 2; ++h) {         // two k-halves of 32
            v8s af[4], bf[4];
#pragma unroll
            for (int mi = 0; mi < 4; mi++) {
                int row = wm + mi * 16 + rsel;
                af[mi] = *(const v8s*)(As + row * 64 + (((h * 4 + kg) ^ (row & 7)) * 8));
            }
#pragma unroll
            for (int ni = 0; ni < 4; ni++) {
                int row = wn + ni * 16 + rsel;
                bf[ni] = *(const v8s*)(Bs + row * 64 + (((h * 4 + kg) ^ (row & 7)) * 8));
            }
#pragma unroll
            for (int mi = 0; mi < 4; mi++)
#pragma unroll
                for (int ni = 0; ni < 4; ni++)
                    acc[mi][ni] = __builtin_amdgcn_mfma_f32_16x16x32_bf16(bf[ni], af[mi], acc[mi][ni], 0, 0, 0);
        }
    }

    // epilogue (swapped layout): m = wm+mi*16+rsel, n = n0+wn+ni*16+kg*4+t
#pragma unroll
    for (int ni = 0; ni < 4; ni++) {
        int nb = n0 + wn + ni * 16 + kg * 4;
        float bv[4];
        if (z == 0) {
            f4 b4 = *(const f4*)(bias + nb);
#pragma unroll
            for (int t = 0; t < 4; ++t) bv[t] = b4[t];
        } else {
#pragma unroll
            for (int t = 0; t < 4; ++t) {
                int nn = nb + t;
                bv[t] = bias[(nn & 15) * 256 + (nn >> 4)];   // un-permute pi
            }
        }
#pragma unroll
        for (int mi = 0; mi < 4; mi++) {
            int m = m0 + wm + mi * 16 + rsel;
            u16x4 pack;
#pragma unroll
            for (int t = 0; t < 4; ++t)
                pack[t] = f2b(fmaxf(acc[mi][ni][t] + bv[t], 0.0f) * RSCALE);
            *(u16x4*)(R + (size_t)m * 4096 + nb) = pack;
        }
    }
}

// ---------------- stage2: q-accumulation; 6 blocks/CU ------------------------
// R pre-scaled: tanh(dot/16) = 1 - 2*rcp(1 + exp2(c)).
// R9 lesson: 8 blocks/CU -> 32 MB in-flight R -> L2 thrash (FETCH 139 MB).
// 4 was safe (16 MB). 6 -> 24 MB <= 32 MB aggregate L2: midpoint probe.
__global__ __launch_bounds__(256, 6) void stage2(
    const u16* __restrict__ Rd, const u16* __restrict__ Rp,
    const float* __restrict__ drug, const float* __restrict__ protein,
    float* __restrict__ out, int bo) {
    int bl = blockIdx.x;
    int b  = bo + bl;
    __shared__ __align__(16) u16 Ad[4096];   // 8 KB; overlaid by rowq/colq
    __shared__ __align__(16) u16 Bp[4096];   // 8 KB
    float* rowq = (float*)Ad;                // 256 f
    float* colq = rowq + 256;                // 1024 f (total 5 KB <= 8 KB)

    int tid = threadIdx.x, lane = tid & 63, wave = tid >> 6;
    {
        const u16* rd = Rd + (size_t)bl * 4096;
        const u16* rp = Rp + (size_t)bl * 4096;
        g2l16(rd + tid * 8,         Ad + tid * 8);
        g2l16(rd + (tid + 256) * 8, Ad + (tid + 256) * 8);
        g2l16(rp + tid * 8,         Bp + tid * 8);
        g2l16(rp + (tid + 256) * 8, Bp + (tid + 256) * 8);
    }
    __syncthreads();   // staging drained (vmcnt) + visible

    int  mr = lane & 15;
    int  kg = lane >> 4;
    int  ko = (kg & 1) * 8;       // kg>=2 lanes duplicate kg 0/1 loads (masked via af)
    bool act = kg < 2;
    v8s zero8 = {};
    v4f czero = {};

    v8s af[4];
#pragma unroll
    for (int s = 0; s < 4; ++s) {
        v8s ld = *(const v8s*)(Ad + (wave * 64 + s * 16 + mr) * 16 + ko);
        af[s] = act ? ld : zero8;
    }
    __syncthreads();   // all waves' Ad reads done; overlay region now writable

    v4f rsq[4] = {czero, czero, czero, czero};
#pragma unroll 2
    for (int ni = 0; ni < 16; ++ni) {
        v8s bf = *(const v8s*)(Bp + (ni * 16 + mr) * 16 + ko);
        v4f cq = czero;
#pragma unroll
        for (int s = 0; s < 4; ++s) {
            v4f c = __builtin_amdgcn_mfma_f32_16x16x32_bf16(af[s], bf, czero, 0, 0, 0);
            v4f q;
#pragma unroll
            for (int t = 0; t < 4; ++t)
                q[t] = RCPF(1.0f + EXP2F(c[t]));
            rsq[s] += q;           // v_pk_add_f32 pairs
            cq += q;
        }
        float cp = (cq[0] + cq[1]) + (cq[2] + cq[3]);
        cp += __shfl_xor(cp, 16);  // sum the 4 kg row-quads
        cp += __shfl_xor(cp, 32);
        if (lane < 16) colq[wave * 256 + ni * 16 + lane] = cp;
    }
#pragma unroll
    for (int s = 0; s < 4; ++s)
#pragma unroll
        for (int t = 0; t < 4; ++t) {
            float v = rsq[s][t];
            v += __shfl_xor(v, 1);
            v += __shfl_xor(v, 2);
            v += __shfl_xor(v, 4);
            v += __shfl_xor(v, 8);
            if (mr == 0) rowq[wave * 64 + s * 16 + kg * 4 + t] = v;
        }
    __syncthreads();
    float qc = colq[tid] + colq[256 + tid] + colq[512 + tid] + colq[768 + tid];
    float ca = tanhp(256.0f - 2.0f * rowq[tid]);   // compound_atte[d=tid]
    float pa = tanhp(256.0f - 2.0f * qc);          // protein_atte[p=tid]
    size_t o = (size_t)b * 256 + tid;
    out[o]           = drug[o]    * ca;
    out[1048576 + o] = protein[o] * pa;
}

// ============================================================================
// Fallback: R6's proven fused zero-workspace kernel (fp32 in, fp32 out).
// ============================================================================
__global__ __launch_bounds__(256) void fused_fallback(
    const float* __restrict__ drug, const float* __restrict__ protein,
    const float* __restrict__ Wd,   const float* __restrict__ bd,
    const float* __restrict__ Wp,   const float* __restrict__ bp,
    float* __restrict__ out)
{
    __shared__ __align__(16) u16 smem[73856];
    u16*   dRow = smem;
    u16*   pRow = smem + 2048;
    u16*   Ws   = smem + 4096;
    float* rowsum  = (float*)(smem + 4096);
    float* colpart = rowsum + 256;
    u16*   dAtt = smem + 8320;
    u16*   pAtt = smem + 41088;

    int tid = threadIdx.x, lane = tid & 63, wave = tid >> 6;
    int b0  = blockIdx.x * 8;
    int mr  = lane & 15;
    int kg  = lane >> 4;
    int ksel = kg * 8;

    {
        int row = tid >> 5, c = (tid & 31) * 8;
        const float* ps = drug + (size_t)(b0 + row) * 256 + c;
        const float* qs = protein + (size_t)(b0 + row) * 256 + c;
        u16x8 r1, r2;
#pragma unroll
        for (int j = 0; j < 8; ++j) { r1[j] = f2b(ps[j]); r2[j] = f2b(qs[j]); }
        *(u16x8*)(dRow + row * 256 + c) = r1;
        *(u16x8*)(pRow + row * 256 + c) = r2;
    }

    int r0 = tid >> 4;
    int c0 = (tid & 15) * 8;
    for (int which = 0; which < 2; ++which) {
        const float* W      = which ? Wp   : Wd;
        const float* bias   = which ? bp   : bd;
        const u16*   rowbuf = which ? pRow : dRow;
        u16*         att    = which ? pAtt : dAtt;

        for (int n0 = 0; n0 < 4096; n0 += 128) {
            v4f acc0 = {}, acc1 = {};
            int wn = wave * 32;
            u16x8 pf0, pf1;
            {
                const float* p0 = W + (size_t)(r0) * 4096 + n0 + c0;
                const float* p1 = W + (size_t)(r0 + 16) * 4096 + n0 + c0;
#pragma unroll
                for (int j = 0; j < 8; ++j) { pf0[j] = f2b(p0[j]); pf1[j] = f2b(p1[j]); }
            }
            for (int k0 = 0; k0 < 256; k0 += 32) {
                __syncthreads();
                *(u16x4*)(Ws + r0 * 132 + c0)            = ((u16x4*)&pf0)[0];
                *(u16x4*)(Ws + r0 * 132 + c0 + 4)        = ((u16x4*)&pf0)[1];
                *(u16x4*)(Ws + (r0 + 16) * 132 + c0)     = ((u16x4*)&pf1)[0];
                *(u16x4*)(Ws + (r0 + 16) * 132 + c0 + 4) = ((u16x4*)&pf1)[1];
                __syncthreads();
                if (k0 + 32 < 256) {
                    const float* p0 = W + (size_t)(k0 + 32 + r0) * 4096 + n0 + c0;
                    const float* p1 = W + (size_t)(k0 + 32 + r0 + 16) * 4096 + n0 + c0;
#pragma unroll
                    for (int j = 0; j < 8; ++j) { pf0[j] = f2b(p0[j]); pf1[j] = f2b(p1[j]); }
                }
                v8s af = {};
                if (mr < 8) af = *(const v8s*)(rowbuf + mr * 256 + k0 + ksel);
                v8s bf0, bf1;
                int nA = wn + mr, nB = wn + 16 + mr;
#pragma unroll
                for (int j = 0; j < 8; ++j) {
                    bf0[j] = (short)Ws[(ksel + j) * 132 + nA];
                    bf1[j] = (short)Ws[(ksel + j) * 132 + nB];
                }
                acc0 = __builtin_amdgcn_mfma_f32_16x16x32_bf16(af, bf0, acc0, 0, 0, 0);
                acc1 = __builtin_amdgcn_mfma_f32_16x16x32_bf16(af, bf1, acc1, 0, 0, 0);
            }
            int colA = n0 + wn + mr, colB = colA + 16;
            float bvA = bias[colA], bvB = bias[colB];
#pragma unroll
            for (int t = 0; t < 4; ++t) {
                int row = kg * 4 + t;
                if (row < 8) {
                    u16 vA = f2b(fmaxf(acc0[t] + bvA, 0.0f));
                    u16 vB = f2b(fmaxf(acc1[t] + bvB, 0.0f));
                    if (which == 0) {
                        att[row * 4096 + colA] = vA;
                        att[row * 4096 + colB] = vB;
                    } else {
                        att[row * 4096 + (colA & 255) * 16 + (colA >> 8)] = vA;
                        att[row * 4096 + (colB & 255) * 16 + (colB >> 8)] = vB;
                    }
                }
            }
        }
    }
    __syncthreads();

    v8s zero8 = {};
    v4f czero = {};
    int  ko2  = (kg & 1) * 8;
    bool act2 = kg < 2;
    for (int r = 0; r < 8; ++r) {
        const u16* Ar = dAtt + r * 4096;
        const u16* Br = pAtt + r * 4096;
        v8s af2[4];
#pragma unroll
        for (int s = 0; s < 4; ++s) {
            int d = wave * 64 + s * 16 + mr;
            v8s ld = *(const v8s*)(Ar + d * 16 + ko2);
            af2[s] = act2 ? ld : zero8;
        }
        float rs[4][4] = {};
#pragma unroll
        for (int ni = 0; ni < 16; ++ni) {
            int p = ni * 16 + mr;
            v8s lb = *(const v8s*)(Br + p * 16 + ko2);
            v8s bf = act2 ? lb : zero8;
            float cp = 0.0f;
#pragma unroll
            for (int s = 0; s < 4; ++s) {
                v4f c = __builtin_amdgcn_mfma_f32_16x16x32_bf16(af2[s], bf, czero, 0, 0, 0);
#pragma unroll
                for (int t = 0; t < 4; ++t) {
                    float v = tanhp(c[t] * 0.0625f);
                    rs[s][t] += v;
                    cp += v;
                }
            }
            cp += __shfl_xor(cp, 16);
            cp += __shfl_xor(cp, 32);
            if (lane < 16) colpart[wave * 256 + ni * 16 + lane] = cp;
        }
#pragma unroll
        for (int s = 0; s < 4; ++s)
#pragma unroll
            for (int t = 0; t < 4; ++t) {
                float v = rs[s][t];
                v += __shfl_xor(v, 1);
                v += __shfl_xor(v, 2);
                v += __shfl_xor(v, 4);
                v += __shfl_xor(v, 8);
                if (mr == 0) rowsum[wave * 64 + s * 16 + kg * 4 + t] = v;
            }
        __syncthreads();
        float cs = colpart[tid] + colpart[256 + tid] + colpart[512 + tid] + colpart[768 + tid];
        float ca = tanhp(rowsum[tid]);
        float pa = tanhp(cs);
        size_t o = (size_t)(b0 + r) * 256 + tid;
        out[o]           = drug[o]    * ca;
        out[1048576 + o] = protein[o] * pa;
        __syncthreads();
    }
}

extern "C" void kernel_launch(void* const* d_in, const int* in_sizes, int n_in,
                              void* d_out, int out_size, void* d_ws, size_t ws_size,
                              hipStream_t stream) {
    (void)in_sizes; (void)n_in; (void)out_size;
    const float* drug    = (const float*)d_in[0];
    const float* protein = (const float*)d_in[1];
    const float* Wd      = (const float*)d_in[2];
    const float* bd      = (const float*)d_in[3];
    const float* Wp      = (const float*)d_in[4];
    const float* bp      = (const float*)d_in[5];
    float* out = (float*)d_out;

    const size_t FIXED = (size_t)8 * 1024 * 1024;   // bytes: Ad,Ap,Wtd,Wtp
    size_t avail = (ws_size > FIXED) ? ws_size - FIXED : 0;
    int chunk = (int)(avail / (2 * 4096 * sizeof(u16)));
    chunk = (chunk / 256) * 256;                     // gemm m-tile is 256
    if (chunk > 4096) chunk = 4096;

    if (chunk >= 256) {
        u16* ws  = (u16*)d_ws;
        u16* Ad  = ws;
        u16* Ap  = Ad + (1u << 20);
        u16* Wtd = Ap + (1u << 20);
        u16* Wtp = Wtd + (1u << 20);
        u16* Rd  = Wtp + (1u << 20);
        u16* Rp  = Rd + (size_t)chunk * 4096;

        prep<<<dim3(1024, 1, 4), 256, 0, stream>>>(drug, protein, Wd, Wp, Ad, Ap, Wtd, Wtp);
        for (int bo = 0; bo < 4096; bo += chunk) {
            int rows = (4096 - bo < chunk) ? (4096 - bo) : chunk;
            gemm_relu<<<dim3(rows / 256, 32, 2), 512, 0, stream>>>(
                Ad + (size_t)bo * 256, Ap + (size_t)bo * 256,
                Wtd, Wtp, bd, bp, Rd, Rp);
            stage2<<<dim3(rows), 256, 0, stream>>>(Rd, Rp, drug, protein, out, bo);
        }
    } else {
        fused_fallback<<<dim3(512), 256, 0, stream>>>(drug, protein, Wd, bd, Wp, bp, out);
    }
}

// Round 12
// 171.574 us; speedup vs baseline: 1.0207x; 1.0207x over previous
//
#include <hip/hip_runtime.h>
#include <stdint.h>

typedef unsigned short u16;
typedef u16   u16x4 __attribute__((ext_vector_type(4)));   // 8 B
typedef u16   u16x8 __attribute__((ext_vector_type(8)));   // 16 B
typedef short v8s   __attribute__((ext_vector_type(8)));   // bf16x8 (4 VGPR)
typedef float v4f   __attribute__((ext_vector_type(4)));
typedef float f4    __attribute__((ext_vector_type(4)));

#if __has_builtin(__builtin_amdgcn_exp2f)
#define EXP2F(x) __builtin_amdgcn_exp2f(x)
#else
#define EXP2F(x) exp2f(x)
#endif
#if __has_builtin(__builtin_amdgcn_rcpf)
#define RCPF(x) __builtin_amdgcn_rcpf(x)
#else
#define RCPF(x) (1.0f/(x))
#endif

__device__ __forceinline__ float b2f(u16 u) {
    unsigned int i = ((unsigned int)u) << 16;
    float f; __builtin_memcpy(&f, &i, 4); return f;
}
__device__ __forceinline__ u16 f2b(float f) {
    unsigned int x; __builtin_memcpy(&x, &f, 4);
    x += 0x7fffu + ((x >> 16) & 1u);   // RNE
    return (u16)(x >> 16);
}
// tanh for x >= 0; inf-safe: exp2(big)=inf, rcp(inf)=0 -> exactly 1.
__device__ __forceinline__ float tanhp(float x) {
    float e = EXP2F(2.8853900817779268f * x);   // e^(2x)
    return 1.0f - 2.0f * RCPF(1.0f + e);
}
__device__ __forceinline__ void g2l16(const u16* g, u16* l) {
    __builtin_amdgcn_global_load_lds(
        (const __attribute__((address_space(1))) unsigned int*)g,
        (__attribute__((address_space(3))) unsigned int*)l, 16, 0, 0);
}

// R pre-scale: s^2 = 2/(16*ln2) so stage2's exp2(dot) = e^(2*dot_true/16)
#define RSCALE 0.42466090f

// ---------------- prep: cvt (z=0,1) + wtrans (z=2,3) in ONE dispatch ---------
__global__ __launch_bounds__(256) void prep(
    const float* __restrict__ drug, const float* __restrict__ protein,
    const float* __restrict__ Wd,   const float* __restrict__ Wp,
    u16* __restrict__ Ad, u16* __restrict__ Ap,
    u16* __restrict__ Wtd, u16* __restrict__ Wtp) {
    int z = blockIdx.z;
    if (z < 2) {
        const float* X = z ? protein : drug;
        u16*         O = z ? Ap : Ad;
        size_t i = ((size_t)blockIdx.x * 256 + threadIdx.x) * 4;
        f4 a = *(const f4*)(X + i);
        u16x4 r;
        r[0] = f2b(a[0]); r[1] = f2b(a[1]); r[2] = f2b(a[2]); r[3] = f2b(a[3]);
        *(u16x4*)(O + i) = r;
    } else {
        int zz = (z == 3);
        const float* W = zz ? Wp : Wd;
        u16*         T = zz ? Wtp : Wtd;
        __shared__ u16 t[32][36];
        int k0 = (blockIdx.x & 7) * 32, n0 = (blockIdx.x >> 3) * 32;
        int r = threadIdx.x >> 3, c = (threadIdx.x & 7) * 4;
        f4 v = *(const f4*)(W + (size_t)(k0 + r) * 4096 + n0 + c);
        t[r][c + 0] = f2b(v[0]); t[r][c + 1] = f2b(v[1]);
        t[r][c + 2] = f2b(v[2]); t[r][c + 3] = f2b(v[3]);
        __syncthreads();
        u16x4 o;
        o.x = t[c + 0][r]; o.y = t[c + 1][r]; o.z = t[c + 2][r]; o.w = t[c + 3][r];
        int n = n0 + r;
        int row = zz ? ((n & 255) * 16 + (n >> 8)) : n;
        *(u16x4*)(T + (size_t)row * 256 + k0 + c) = o;
    }
}

// ---------------- GEMM + bias + relu: 128x128 tile, BK=128 -------------------
// R12 experiment: HALF the barrier drains (2 staging rounds for K=256 instead
// of 4), 64 KB LDS at 2 blocks/CU so one block's compute covers the other's
// vmcnt drain. XOR swizzle generalized to 16 chunks/row (^(row&15)):
// staging lane-linear (g2l16-legal), frag ds_read_b128 2-way (free).
// K ascending order preserved -> bit-identical accumulation vs R10/R11.
// mfma(bf, af) operand swap -> packed 8B epilogue stores (R10-verified).
__global__ __launch_bounds__(256, 2) void gemm_relu(
    const u16* __restrict__ A0, const u16* __restrict__ A1,
    const u16* __restrict__ B0, const u16* __restrict__ B1,
    const float* __restrict__ bias0, const float* __restrict__ bias1,
    u16* __restrict__ R0, u16* __restrict__ R1) {
    int z = blockIdx.z;
    const u16*   A    = z ? A1 : A0;
    const u16*   Bt   = z ? B1 : B0;
    const float* bias = z ? bias1 : bias0;
    u16*         R    = z ? R1 : R0;

    __shared__ __align__(16) u16 As[128 * 128];   // 32 KB
    __shared__ __align__(16) u16 Bs[128 * 128];   // 32 KB

    int tid  = threadIdx.x;
    int lane = tid & 63;
    int wave = tid >> 6;                // 0..3
    int m0 = blockIdx.x * 128, n0 = blockIdx.y * 128;
    int wm = (wave >> 1) * 64, wn = (wave & 1) * 64;

    v4f acc[4][4] = {};

    const u16* Ab = A  + (size_t)m0 * 256;
    const u16* Bb = Bt + (size_t)n0 * 256;
    int rsel = lane & 15, kg = lane >> 4;

    for (int kk = 0; kk < 256; kk += 128) {
        __syncthreads();                      // previous round's readers done
#pragma unroll
        for (int j = 0; j < 8; ++j) {         // As: 2048 chunks of 16B
            int f = tid + j * 256;
            int r = f >> 4, cc = f & 15;
            int gc = (cc ^ (r & 15)) * 8;     // swizzled global k-chunk
            g2l16(Ab + (size_t)r * 256 + kk + gc, As + f * 8);
        }
#pragma unroll
        for (int j = 0; j < 8; ++j) {         // Bs: 2048 chunks
            int f = tid + j * 256;
            int r = f >> 4, cc = f & 15;
            int gc = (cc ^ (r & 15)) * 8;
            g2l16(Bb + (size_t)r * 256 + kk + gc, Bs + f * 8);
        }
        __syncthreads();                      // staging complete (vmcnt drained)
#pragma unroll
        for (int h = 0; h < 4; ++h) {         // four k-slices of 32
            v8s af[4], bf[4];
#pragma unroll
            for (int mi = 0; mi < 4; mi++) {
                int row = wm + mi * 16 + rsel;
                af[mi] = *(const v8s*)(As + row * 128 + (((h * 4 + kg) ^ (row & 15)) * 8));
            }
#pragma unroll
            for (int ni = 0; ni < 4; ni++) {
                int row = wn + ni * 16 + rsel;
                bf[ni] = *(const v8s*)(Bs + row * 128 + (((h * 4 + kg) ^ (row & 15)) * 8));
            }
#pragma unroll
            for (int mi = 0; mi < 4; mi++)
#pragma unroll
                for (int ni = 0; ni < 4; ni++)
                    acc[mi][ni] = __builtin_amdgcn_mfma_f32_16x16x32_bf16(bf[ni], af[mi], acc[mi][ni], 0, 0, 0);
        }
    }

    // epilogue (swapped layout): m = wm+mi*16+rsel, n = n0+wn+ni*16+kg*4+t
#pragma unroll
    for (int ni = 0; ni < 4; ni++) {
        int nb = n0 + wn + ni * 16 + kg * 4;
        float bv[4];
        if (z == 0) {
            f4 b4 = *(const f4*)(bias + nb);
#pragma unroll
            for (int t = 0; t < 4; ++t) bv[t] = b4[t];
        } else {
#pragma unroll
            for (int t = 0; t < 4; ++t) {
                int nn = nb + t;
                bv[t] = bias[(nn & 15) * 256 + (nn >> 4)];   // un-permute pi
            }
        }
#pragma unroll
        for (int mi = 0; mi < 4; mi++) {
            int m = m0 + wm + mi * 16 + rsel;
            u16x4 pack;
#pragma unroll
            for (int t = 0; t < 4; ++t)
                pack[t] = f2b(fmaxf(acc[mi][ni][t] + bv[t], 0.0f) * RSCALE);
            *(u16x4*)(R + (size_t)m * 4096 + nb) = pack;
        }
    }
}

// ---------------- stage2: q-accumulation; 4 blocks/CU (R10-best) -------------
// R pre-scaled: tanh(dot/16) = 1 - 2*rcp(1 + exp2(c)).
// R9: 8 blocks/CU thrashes L2 (32 MB in-flight R). R11: 6 neutral-to-worse
// (67.6 vs 66.7). Lock at 4.
__global__ __launch_bounds__(256, 4) void stage2(
    const u16* __restrict__ Rd, const u16* __restrict__ Rp,
    const float* __restrict__ drug, const float* __restrict__ protein,
    float* __restrict__ out, int bo) {
    int bl = blockIdx.x;
    int b  = bo + bl;
    __shared__ __align__(16) u16 Ad[4096];   // 8 KB; overlaid by rowq/colq
    __shared__ __align__(16) u16 Bp[4096];   // 8 KB
    float* rowq = (float*)Ad;                // 256 f
    float* colq = rowq + 256;                // 1024 f (total 5 KB <= 8 KB)

    int tid = threadIdx.x, lane = tid & 63, wave = tid >> 6;
    {
        const u16* rd = Rd + (size_t)bl * 4096;
        const u16* rp = Rp + (size_t)bl * 4096;
        g2l16(rd + tid * 8,         Ad + tid * 8);
        g2l16(rd + (tid + 256) * 8, Ad + (tid + 256) * 8);
        g2l16(rp + tid * 8,         Bp + tid * 8);
        g2l16(rp + (tid + 256) * 8, Bp + (tid + 256) * 8);
    }
    __syncthreads();   // staging drained (vmcnt) + visible

    int  mr = lane & 15;
    int  kg = lane >> 4;
    int  ko = (kg & 1) * 8;       // kg>=2 lanes duplicate kg 0/1 loads (masked via af)
    bool act = kg < 2;
    v8s zero8 = {};
    v4f czero = {};

    v8s af[4];
#pragma unroll
    for (int s = 0; s < 4; ++s) {
        v8s ld = *(const v8s*)(Ad + (wave * 64 + s * 16 + mr) * 16 + ko);
        af[s] = act ? ld : zero8;
    }
    __syncthreads();   // all waves' Ad reads done; overlay region now writable

    v4f rsq[4] = {czero, czero, czero, czero};
#pragma unroll 2
    for (int ni = 0; ni < 16; ++ni) {
        v8s bf = *(const v8s*)(Bp + (ni * 16 + mr) * 16 + ko);
        v4f cq = czero;
#pragma unroll
        for (int s = 0; s < 4; ++s) {
            v4f c = __builtin_amdgcn_mfma_f32_16x16x32_bf16(af[s], bf, czero, 0, 0, 0);
            v4f q;
#pragma unroll
            for (int t = 0; t < 4; ++t)
                q[t] = RCPF(1.0f + EXP2F(c[t]));
            rsq[s] += q;           // v_pk_add_f32 pairs
            cq += q;
        }
        float cp = (cq[0] + cq[1]) + (cq[2] + cq[3]);
        cp += __shfl_xor(cp, 16);  // sum the 4 kg row-quads
        cp += __shfl_xor(cp, 32);
        if (lane < 16) colq[wave * 256 + ni * 16 + lane] = cp;
    }
#pragma unroll
    for (int s = 0; s < 4; ++s)
#pragma unroll
        for (int t = 0; t < 4; ++t) {
            float v = rsq[s][t];
            v += __shfl_xor(v, 1);
            v += __shfl_xor(v, 2);
            v += __shfl_xor(v, 4);
            v += __shfl_xor(v, 8);
            if (mr == 0) rowq[wave * 64 + s * 16 + kg * 4 + t] = v;
        }
    __syncthreads();
    float qc = colq[tid] + colq[256 + tid] + colq[512 + tid] + colq[768 + tid];
    float ca = tanhp(256.0f - 2.0f * rowq[tid]);   // compound_atte[d=tid]
    float pa = tanhp(256.0f - 2.0f * qc);          // protein_atte[p=tid]
    size_t o = (size_t)b * 256 + tid;
    out[o]           = drug[o]    * ca;
    out[1048576 + o] = protein[o] * pa;
}

// ============================================================================
// Fallback: R6's proven fused zero-workspace kernel (fp32 in, fp32 out).
// ============================================================================
__global__ __launch_bounds__(256) void fused_fallback(
    const float* __restrict__ drug, const float* __restrict__ protein,
    const float* __restrict__ Wd,   const float* __restrict__ bd,
    const float* __restrict__ Wp,   const float* __restrict__ bp,
    float* __restrict__ out)
{
    __shared__ __align__(16) u16 smem[73856];
    u16*   dRow = smem;
    u16*   pRow = smem + 2048;
    u16*   Ws   = smem + 4096;
    float* rowsum  = (float*)(smem + 4096);
    float* colpart = rowsum + 256;
    u16*   dAtt = smem + 8320;
    u16*   pAtt = smem + 41088;

    int tid = threadIdx.x, lane = tid & 63, wave = tid >> 6;
    int b0  = blockIdx.x * 8;
    int mr  = lane & 15;
    int kg  = lane >> 4;
    int ksel = kg * 8;

    {
        int row = tid >> 5, c = (tid & 31) * 8;
        const float* ps = drug + (size_t)(b0 + row) * 256 + c;
        const float* qs = protein + (size_t)(b0 + row) * 256 + c;
        u16x8 r1, r2;
#pragma unroll
        for (int j = 0; j < 8; ++j) { r1[j] = f2b(ps[j]); r2[j] = f2b(qs[j]); }
        *(u16x8*)(dRow + row * 256 + c) = r1;
        *(u16x8*)(pRow + row * 256 + c) = r2;
    }

    int r0 = tid >> 4;
    int c0 = (tid & 15) * 8;
    for (int which = 0; which < 2; ++which) {
        const float* W      = which ? Wp   : Wd;
        const float* bias   = which ? bp   : bd;
        const u16*   rowbuf = which ? pRow : dRow;
        u16*         att    = which ? pAtt : dAtt;

        for (int n0 = 0; n0 < 4096; n0 += 128) {
            v4f acc0 = {}, acc1 = {};
            int wn = wave * 32;
            u16x8 pf0, pf1;
            {
                const float* p0 = W + (size_t)(r0) * 4096 + n0 + c0;
                const float* p1 = W + (size_t)(r0 + 16) * 4096 + n0 + c0;
#pragma unroll
                for (int j = 0; j < 8; ++j) { pf0[j] = f2b(p0[j]); pf1[j] = f2b(p1[j]); }
            }
            for (int k0 = 0; k0 < 256; k0 += 32) {
                __syncthreads();
                *(u16x4*)(Ws + r0 * 132 + c0)            = ((u16x4*)&pf0)[0];
                *(u16x4*)(Ws + r0 * 132 + c0 + 4)        = ((u16x4*)&pf0)[1];
                *(u16x4*)(Ws + (r0 + 16) * 132 + c0)     = ((u16x4*)&pf1)[0];
                *(u16x4*)(Ws + (r0 + 16) * 132 + c0 + 4) = ((u16x4*)&pf1)[1];
                __syncthreads();
                if (k0 + 32 < 256) {
                    const float* p0 = W + (size_t)(k0 + 32 + r0) * 4096 + n0 + c0;
                    const float* p1 = W + (size_t)(k0 + 32 + r0 + 16) * 4096 + n0 + c0;
#pragma unroll
                    for (int j = 0; j < 8; ++j) { pf0[j] = f2b(p0[j]); pf1[j] = f2b(p1[j]); }
                }
                v8s af = {};
                if (mr < 8) af = *(const v8s*)(rowbuf + mr * 256 + k0 + ksel);
                v8s bf0, bf1;
                int nA = wn + mr, nB = wn + 16 + mr;
#pragma unroll
                for (int j = 0; j < 8; ++j) {
                    bf0[j] = (short)Ws[(ksel + j) * 132 + nA];
                    bf1[j] = (short)Ws[(ksel + j) * 132 + nB];
                }
                acc0 = __builtin_amdgcn_mfma_f32_16x16x32_bf16(af, bf0, acc0, 0, 0, 0);
                acc1 = __builtin_amdgcn_mfma_f32_16x16x32_bf16(af, bf1, acc1, 0, 0, 0);
            }
            int colA = n0 + wn + mr, colB = colA + 16;
            float bvA = bias[colA], bvB = bias[colB];
#pragma unroll
            for (int t = 0; t < 4; ++t) {
                int row = kg * 4 + t;
                if (row < 8) {
                    u16 vA = f2b(fmaxf(acc0[t] + bvA, 0.0f));
                    u16 vB = f2b(fmaxf(acc1[t] + bvB, 0.0f));
                    if (which == 0) {
                        att[row * 4096 + colA] = vA;
                        att[row * 4096 + colB] = vB;
                    } else {
                        att[row * 4096 + (colA & 255) * 16 + (colA >> 8)] = vA;
                        att[row * 4096 + (colB & 255) * 16 + (colB >> 8)] = vB;
                    }
                }
            }
        }
    }
    __syncthreads();

    v8s zero8 = {};
    v4f czero = {};
    int  ko2  = (kg & 1) * 8;
    bool act2 = kg < 2;
    for (int r = 0; r < 8; ++r) {
        const u16* Ar = dAtt + r * 4096;
        const u16* Br = pAtt + r * 4096;
        v8s af2[4];
#pragma unroll
        for (int s = 0; s < 4; ++s) {
            int d = wave * 64 + s * 16 + mr;
            v8s ld = *(const v8s*)(Ar + d * 16 + ko2);
            af2[s] = act2 ? ld : zero8;
        }
        float rs[4][4] = {};
#pragma unroll
        for (int ni = 0; ni < 16; ++ni) {
            int p = ni * 16 + mr;
            v8s lb = *(const v8s*)(Br + p * 16 + ko2);
            v8s bf = act2 ? lb : zero8;
            float cp = 0.0f;
#pragma unroll
            for (int s = 0; s < 4; ++s) {
                v4f c = __builtin_amdgcn_mfma_f32_16x16x32_bf16(af2[s], bf, czero, 0, 0, 0);
#pragma unroll
                for (int t = 0; t < 4; ++t) {
                    float v = tanhp(c[t] * 0.0625f);
                    rs[s][t] += v;
                    cp += v;
                }
            }
            cp += __shfl_xor(cp, 16);
            cp += __shfl_xor(cp, 32);
            if (lane < 16) colpart[wave * 256 + ni * 16 + lane] = cp;
        }
#pragma unroll
        for (int s = 0; s < 4; ++s)
#pragma unroll
            for (int t = 0; t < 4; ++t) {
                float v = rs[s][t];
                v += __shfl_xor(v, 1);
                v += __shfl_xor(v, 2);
                v += __shfl_xor(v, 4);
                v += __shfl_xor(v, 8);
                if (mr == 0) rowsum[wave * 64 + s * 16 + kg * 4 + t] = v;
            }
        __syncthreads();
        float cs = colpart[tid] + colpart[256 + tid] + colpart[512 + tid] + colpart[768 + tid];
        float ca = tanhp(rowsum[tid]);
        float pa = tanhp(cs);
        size_t o = (size_t)(b0 + r) * 256 + tid;
        out[o]           = drug[o]    * ca;
        out[1048576 + o] = protein[o] * pa;
        __syncthreads();
    }
}

extern "C" void kernel_launch(void* const* d_in, const int* in_sizes, int n_in,
                              void* d_out, int out_size, void* d_ws, size_t ws_size,
                              hipStream_t stream) {
    (void)in_sizes; (void)n_in; (void)out_size;
    const float* drug    = (const float*)d_in[0];
    const float* protein = (const float*)d_in[1];
    const float* Wd      = (const float*)d_in[2];
    const float* bd      = (const float*)d_in[3];
    const float* Wp      = (const float*)d_in[4];
    const float* bp      = (const float*)d_in[5];
    float* out = (float*)d_out;

    const size_t FIXED = (size_t)8 * 1024 * 1024;   // bytes: Ad,Ap,Wtd,Wtp
    size_t avail = (ws_size > FIXED) ? ws_size - FIXED : 0;
    int chunk = (int)(avail / (2 * 4096 * sizeof(u16)));
    chunk = (chunk / 128) * 128;                     // gemm m-tile is 128
    if (chunk > 4096) chunk = 4096;

    if (chunk >= 128) {
        u16* ws  = (u16*)d_ws;
        u16* Ad  = ws;
        u16* Ap  = Ad + (1u << 20);
        u16* Wtd = Ap + (1u << 20);
        u16* Wtp = Wtd + (1u << 20);
        u16* Rd  = Wtp + (1u << 20);
        u16* Rp  = Rd + (size_t)chunk * 4096;

        prep<<<dim3(1024, 1, 4), 256, 0, stream>>>(drug, protein, Wd, Wp, Ad, Ap, Wtd, Wtp);
        for (int bo = 0; bo < 4096; bo += chunk) {
            int rows = (4096 - bo < chunk) ? (4096 - bo) : chunk;
            gemm_relu<<<dim3(rows / 128, 32, 2), 256, 0, stream>>>(
                Ad + (size_t)bo * 256, Ap + (size_t)bo * 256,
                Wtd, Wtp, bd, bp, Rd, Rp);
            stage2<<<dim3(rows), 256, 0, stream>>>(Rd, Rp, drug, protein, out, bo);
        }
    } else {
        fused_fallback<<<dim3(512), 256, 0, stream>>>(drug, protein, Wd, bd, Wp, bp, out);
    }
}